// Round 4
// baseline (177.854 us; speedup 1.0000x reference)
//
#include <hip/hip_runtime.h>

// PositionNet fused, MFMA bf16x3, N-split-per-wave edition.
//   hm = softmax(conv1x1(img_feat))  -> [512,25,8,8,8]
//   coords = soft-argmax(hm)         -> [512,25,3]
//
// Per sample (block): [64 px x 768 ch] x [768 ch x 200 out], K-tiled by 32,
// v_mfma_f32_16x16x32_bf16 with bf16 hi/lo split (hh + hl + lh) for ~fp32
// logit accuracy (~2^-17 rel).
//  - Waves split over N: wave w owns N-tiles {w, w+4, w+8, w+12} for ALL 4
//    M-tiles -> each B fragment consumed by exactly one wave -> B is loaded
//    DIRECTLY global->VGPR (1 KiB coalesced dwordx4 per fragment, L2-hot
//    weights; no LDS staging, no barrier dependency).
//  - Only A (shared across waves, needs transpose+split) goes through LDS.
//    Row stride 40 shorts -> single aligned ds_read_b128 fragments,
//    bank-balanced.
//  - Weights pre-split into d_ws (688,128 B) by a tiny pre-kernel; rows
//    200..223 zero-padded.
// Fragment k-addressing identical for A and B (kk0 = (lane>>4)*8), so any
// hardware k-slot permutation cancels; relies only on lane&15 = free-dim and
// the m89-verified C/D layout (col=lane&15, row=(lane>>4)*4+reg).

typedef __attribute__((ext_vector_type(4))) float f32x4;
typedef __attribute__((ext_vector_type(8))) short bf16x8;
typedef __attribute__((ext_vector_type(4))) unsigned int u32x4;

namespace {
constexpr int kB = 512, kC = 768, kP = 64, kO = 200, kJ = 25;
constexpr int kKT = 32, kSteps = 24;  // K = 24 steps x 32 channels
constexpr int kNP = 224, kNT = 13;    // N padded to 224; 13 live 16-wide tiles
constexpr int kAR = 40;  // LDS A row stride (shorts) = 80 B -> 16B-aligned frags
constexpr int kHR = 67;  // hm row stride (floats); 67*16 % 32 spreads banks
constexpr int kWsHalf = kSteps * kNP * kKT;  // 172032 shorts per (hi|lo) half
constexpr size_t kHmOut = (size_t)kB * kJ * 512;
constexpr int kOffAlo = kP * kAR * 2;     // 5120 B
constexpr int kSmemBytes = kO * kHR * 4;  // 53600 B (hm view; > 10240 staging)
}  // namespace

__device__ inline unsigned short f2bf(float x) {  // RNE fp32 -> bf16 bits
  union { float f; unsigned u; } c; c.f = x;
  unsigned r = c.u + 0x7FFFu + ((c.u >> 16) & 1u);
  return (unsigned short)(r >> 16);
}
__device__ inline float bf2f(unsigned short h) {
  union { unsigned u; float f; } c; c.u = ((unsigned)h) << 16;
  return c.f;
}

// ---- pre-kernel: w[200][768] fp32 -> ws: hi[24][224][32] ++ lo[...] bf16 ----
__global__ __launch_bounds__(256) void weight_split_kernel(
    const float* __restrict__ w, unsigned short* __restrict__ ws) {
  const int id = blockIdx.x * 256 + threadIdx.x;
  if (id >= kSteps * kNP * 8) return;
  const int t = id / (kNP * 8);
  const int rem = id - t * (kNP * 8);
  const int n = rem >> 3;
  const int kk = (rem & 7) * 4;
  f32x4 v = {0.f, 0.f, 0.f, 0.f};
  if (n < kO) v = *(const f32x4*)(w + (size_t)n * kC + t * kKT + kk);
  unsigned short hi[4], lo[4];
#pragma unroll
  for (int i = 0; i < 4; ++i) {
    hi[i] = f2bf(v[i]);
    lo[i] = f2bf(v[i] - bf2f(hi[i]));
  }
  const size_t base = (size_t)(t * kNP + n) * kKT + kk;
  typedef __attribute__((ext_vector_type(4))) unsigned short us4;
  *(us4*)(ws + base) = us4{hi[0], hi[1], hi[2], hi[3]};
  *(us4*)(ws + kWsHalf + base) = us4{lo[0], lo[1], lo[2], lo[3]};
}

__global__ __launch_bounds__(256, 2) void posnet_fused_kernel(
    const float* __restrict__ img, const unsigned short* __restrict__ wsb,
    const float* __restrict__ bias, float* __restrict__ out) {
  __shared__ __align__(16) char smem[kSmemBytes];  // union: A staging | hm
  __shared__ float ldsBias[kO];
  unsigned short* ldsAhi = (unsigned short*)smem;
  unsigned short* ldsAlo = (unsigned short*)(smem + kOffAlo);
  float* hm = (float*)smem;  // [200][67] fp32, post-GEMM

  const int b = blockIdx.x;
  const int tid = threadIdx.x;
  const int lane = tid & 63;
  const int wid = tid >> 6;  // wave id -> N-tile round-robin
  const float* __restrict__ imgb = img + (size_t)b * kC * kP;

  if (tid < kO) ldsBias[tid] = bias[tid];

  const int m_l = lane & 15;  // free-dim index within a 16-tile
  const int g = lane >> 4;    // k-slot group
  const int kk0 = g * 8;      // k base, same addressing for A and B

  f32x4 acc[4][4];  // [ni][mt]
#pragma unroll
  for (int i = 0; i < 4; ++i)
#pragma unroll
    for (int j = 0; j < 4; ++j) acc[i][j] = f32x4{0.f, 0.f, 0.f, 0.f};

  const int sp = tid & 63;         // staging: pixel
  const int sc0 = (tid >> 6) * 8;  // staging: channel base within K-tile

  for (int t = 0; t < kSteps; ++t) {
    __syncthreads();  // previous iteration's A-frag reads complete
    // ---- stage A: img [c][p] fp32 -> LDS [p][c] bf16 hi/lo (exact split) ----
    {
      const float* src = imgb + (size_t)(t * kKT + sc0) * kP + sp;
      unsigned u[8];
#pragma unroll
      for (int i = 0; i < 8; ++i) u[i] = __float_as_uint(src[(size_t)i * kP]);
      unsigned ph[4], pl[4];
#pragma unroll
      for (int i = 0; i < 4; ++i) {
        const unsigned a = u[2 * i], c = u[2 * i + 1];
        const unsigned am = a & 0xFFFF0000u, cm = c & 0xFFFF0000u;
        ph[i] = (a >> 16) | cm;  // hi = trunc16; exact residual below
        const float la = __uint_as_float(a) - __uint_as_float(am);
        const float lc = __uint_as_float(c) - __uint_as_float(cm);
        pl[i] = (__float_as_uint(la) >> 16) | (__float_as_uint(lc) & 0xFFFF0000u);
      }
      *(u32x4*)(ldsAhi + sp * kAR + sc0) = u32x4{ph[0], ph[1], ph[2], ph[3]};
      *(u32x4*)(ldsAlo + sp * kAR + sc0) = u32x4{pl[0], pl[1], pl[2], pl[3]};
    }
    // ---- B fragments: direct global->VGPR (L2-hot), 1 KiB coalesced each ----
    bf16x8 bhi[4], blo[4];
#pragma unroll
    for (int ni = 0; ni < 4; ++ni) {
      const int nt = ni * 4 + wid;  // wave-uniform
      if (nt < kNT) {
        const unsigned short* bs =
            wsb + ((size_t)t * kNP + nt * 16 + m_l) * kKT + kk0;
        bhi[ni] = *(const bf16x8*)bs;
        blo[ni] = *(const bf16x8*)(bs + kWsHalf);
      }
    }
    __syncthreads();  // A staged & visible
    // ---- A fragments: single aligned ds_read_b128 each ----
    bf16x8 ahi[4], alo[4];
#pragma unroll
    for (int mt = 0; mt < 4; ++mt) {
      const int row = mt * 16 + m_l;
      ahi[mt] = *(const bf16x8*)(ldsAhi + row * kAR + kk0);
      alo[mt] = *(const bf16x8*)(ldsAlo + row * kAR + kk0);
    }
    // ---- MFMA: hh + hl + lh ----
#pragma unroll
    for (int ni = 0; ni < 4; ++ni) {
      const int nt = ni * 4 + wid;
      if (nt < kNT) {
#pragma unroll
        for (int mt = 0; mt < 4; ++mt) {
          acc[ni][mt] = __builtin_amdgcn_mfma_f32_16x16x32_bf16(
              ahi[mt], bhi[ni], acc[ni][mt], 0, 0, 0);
          acc[ni][mt] = __builtin_amdgcn_mfma_f32_16x16x32_bf16(
              ahi[mt], blo[ni], acc[ni][mt], 0, 0, 0);
          acc[ni][mt] = __builtin_amdgcn_mfma_f32_16x16x32_bf16(
              alo[mt], bhi[ni], acc[ni][mt], 0, 0, 0);
        }
      }
    }
  }
  __syncthreads();  // all A reads done; smem becomes hm

  // ---- logits (+bias) -> hm. C/D: col(o)=lane&15, row(m)=(lane>>4)*4+r ----
#pragma unroll
  for (int ni = 0; ni < 4; ++ni) {
    const int nt = ni * 4 + wid;
    if (nt < kNT) {
      const int o = nt * 16 + m_l;
      if (o < kO) {
        const float bo = ldsBias[o];
#pragma unroll
        for (int mt = 0; mt < 4; ++mt) {
          const int m = mt * 16 + g * 4;
#pragma unroll
          for (int r = 0; r < 4; ++r) hm[o * kHR + m + r] = acc[ni][mt][r] + bo;
        }
      }
    }
  }
  __syncthreads();

  // ---- softmax over 512 + soft-argmax; joints round-robin over waves ----
  for (int j = wid; j < kJ; j += 4) {
    float v[8];
#pragma unroll
    for (int k = 0; k < 8; ++k) v[k] = hm[(j * 8 + k) * kHR + lane];

    float m = v[0];
#pragma unroll
    for (int k = 1; k < 8; ++k) m = fmaxf(m, v[k]);
#pragma unroll
    for (int off = 32; off > 0; off >>= 1) m = fmaxf(m, __shfl_xor(m, off));

    float e[8];
    float s = 0.f;
#pragma unroll
    for (int k = 0; k < 8; ++k) {
      e[k] = __expf(v[k] - m);
      s += e[k];
    }
#pragma unroll
    for (int off = 32; off > 0; off >>= 1) s += __shfl_xor(s, off);
    const float inv = 1.0f / s;

    float psum = 0.f, zsum = 0.f;
    float* dst = out + ((size_t)b * kJ + j) * 512;
#pragma unroll
    for (int k = 0; k < 8; ++k) {
      const float pv = e[k] * inv;
      dst[k * 64 + lane] = pv;  // coalesced 256B stores
      psum += pv;
      zsum += (float)k * pv;    // depth index = k
    }
    float xs = (float)(lane & 7) * psum;   // lane = h*8+w -> w = lane&7
    float ys = (float)(lane >> 3) * psum;  // h = lane>>3
#pragma unroll
    for (int off = 32; off > 0; off >>= 1) {
      xs += __shfl_xor(xs, off);
      ys += __shfl_xor(ys, off);
      zsum += __shfl_xor(zsum, off);
    }
    if (lane == 0) {
      float* cd = out + kHmOut + ((size_t)b * kJ + j) * 3;
      cd[0] = xs;
      cd[1] = ys;
      cd[2] = zsum;
    }
  }
}

extern "C" void kernel_launch(void* const* d_in, const int* in_sizes, int n_in,
                              void* d_out, int out_size, void* d_ws,
                              size_t ws_size, hipStream_t stream) {
  const float* img = (const float*)d_in[0];   // [512,768,8,8]
  const float* w = (const float*)d_in[1];     // [200,768]
  const float* bias = (const float*)d_in[2];  // [200]
  unsigned short* wsb = (unsigned short*)d_ws;  // needs 688,128 B
  float* out = (float*)d_out;

  const int pre_tasks = kSteps * kNP * 8;  // 43008
  weight_split_kernel<<<dim3((pre_tasks + 255) / 256), dim3(256), 0, stream>>>(w, wsb);
  posnet_fused_kernel<<<dim3(kB), dim3(256), 0, stream>>>(img, wsb, bias, out);
}